// Round 5
// baseline (2965.693 us; speedup 1.0000x reference)
//
#include <hip/hip_runtime.h>

typedef unsigned int u32;
typedef unsigned short u16;
using v4f    = __attribute__((ext_vector_type(4))) float;
using short8 = __attribute__((ext_vector_type(8))) short;

#define GAS __attribute__((address_space(1)))
#define LAS __attribute__((address_space(3)))

// ---- bf16 helpers (RNE, matches HW convert; inputs are finite) ----
__device__ __forceinline__ u16 f2bf(float f){
  u32 u = __builtin_bit_cast(u32, f);
  u32 r = (u + 0x7fffu + ((u >> 16) & 1u)) >> 16;
  return (u16)r;
}
__device__ __forceinline__ float bf2f(u16 h){
  u32 u = ((u32)h) << 16;
  return __builtin_bit_cast(float, u);
}

// async global->LDS, 16B per lane. LDS dest must be wave-uniform base + lane*16.
__device__ __forceinline__ void gld_lds16(const void* g, void* l){
  __builtin_amdgcn_global_load_lds((const GAS u32*)g, (LAS u32*)l, 16, 0, 0);
}

// ---- transpose fp32 [K][N] -> bf16 [N][K] (weights only) ----
__global__ __launch_bounds__(256) void transpose_w_bf16(
    const float* __restrict__ in, u16* __restrict__ out, int K, int N)
{
  __shared__ float t[64][65];
  const int k0 = blockIdx.x * 64, n0 = blockIdx.y * 64;
  const int tx = threadIdx.x & 63, ty = threadIdx.x >> 6;
  #pragma unroll
  for (int i = 0; i < 16; i++){
    int r = ty + i * 4;
    t[r][tx] = in[(size_t)(k0 + r) * N + (n0 + tx)];
  }
  __syncthreads();
  #pragma unroll
  for (int i = 0; i < 16; i++){
    int r = ty + i * 4;
    out[(size_t)(n0 + r) * K + (k0 + tx)] = f2bf(t[tx][r]);
  }
}

// ---- in-place softmax, one WAVE per 2048-elem row (4 rows/block) ----
__global__ __launch_bounds__(256) void softmax_rows(u16* __restrict__ S){
  const int lane = threadIdx.x & 63, wid = threadIdx.x >> 6;
  u16* p = S + ((size_t)blockIdx.x * 4 + wid) * 2048;
  uint4 u[4];
  #pragma unroll
  for (int j = 0; j < 4; j++) u[j] = ((const uint4*)p)[lane + j * 64];
  float f[32];
  #pragma unroll
  for (int j = 0; j < 4; j++){
    u32 w4[4] = {u[j].x, u[j].y, u[j].z, u[j].w};
    #pragma unroll
    for (int i = 0; i < 4; i++){
      f[j * 8 + 2*i]     = bf2f((u16)(w4[i] & 0xffffu));
      f[j * 8 + 2*i + 1] = bf2f((u16)(w4[i] >> 16));
    }
  }
  float m = f[0];
  #pragma unroll
  for (int i = 1; i < 32; i++) m = fmaxf(m, f[i]);
  #pragma unroll
  for (int o = 32; o >= 1; o >>= 1) m = fmaxf(m, __shfl_xor(m, o));
  float s = 0.f;
  #pragma unroll
  for (int i = 0; i < 32; i++){ f[i] = __expf(f[i] - m); s += f[i]; }
  #pragma unroll
  for (int o = 32; o >= 1; o >>= 1) s += __shfl_xor(s, o);
  const float inv = 1.f / s;
  #pragma unroll
  for (int j = 0; j < 4; j++){
    u32 w4[4];
    #pragma unroll
    for (int i = 0; i < 4; i++)
      w4[i] = (u32)f2bf(f[j * 8 + 2*i] * inv) |
              ((u32)f2bf(f[j * 8 + 2*i + 1] * inv) << 16);
    ((uint4*)p)[lane + j * 64] = make_uint4(w4[0], w4[1], w4[2], w4[3]);
  }
}

// ===========================================================================
// 128x256x32 bf16 GEMM, OCCUPANCY-FIRST geometry: 48 KiB LDS double-buffer
//   -> 3 blocks/CU co-resident (was 1 at 128 KiB). Free-flow body (measured
//   best r2/r4): single tile-top {lgkmcnt0+vmcnt0+barrier}, then stage next
//   slab, then ds_read + MFMA free-flow. Cross-block overlap fills the
//   latency bubbles the single-block schedule variants couldn't (m114).
//   512 threads = 8 waves (2M x 4N), per-wave output 64x64 (acc[4][4]).
// LDS swizzle (BK=32, 64B rows): slot (r,c4) holds global k-chunk
//   c4 ^ ((r>>1)&3); reads apply the same XOR -> per-lane-const offsets,
//   2-way bank aliasing (free, m136). Involution on both sides.
// AMODE: 0 = A fp32 global, reg-staged (load early / cvt+ds_write late)
//        1 = A bf16 via global_load_lds
//        2 = A concat(qp,x) bf16 (K split at 1024; 32|1024 -> wave-uniform)
// EPI:   0 = +bias, bf16   1 = *scale, bf16   2 = gate-fused, fp32
//        3 = +bias, bf16 TRANSPOSED [batch][col][rowlocal]
// Grid: gridDim.x = n-tiles (pow2), gridDim.y = m-tiles (mult of 8);
//   GROUP-8 swizzle: 8 consecutive blocks share a B-panel, walk 8 A-panels.
// ===========================================================================
template<int AMODE, int EPI>
__global__ __launch_bounds__(512, 6) void gemm256(
    const float* __restrict__ Af,
    const u16* __restrict__ Ab,
    const u16* __restrict__ A2b,
    const u16* __restrict__ BT,
    int lda, int ldb, int K,
    void* __restrict__ Cout, int ldc,
    const float* __restrict__ bias, float scale,
    size_t aBatch, size_t bBatch, size_t cBatch,
    const u16* __restrict__ xg,
    const float* __restrict__ maskp,
    const float* __restrict__ q0p)
{
  constexpr int BK = 32;
  __shared__ __align__(16) u16 As[2][128 * 32];   // [buf][r*32 + c4*8 + e] 16KB
  __shared__ __align__(16) u16 Bs[2][256 * 32];   //                        32KB

  const int z   = blockIdx.z;
  const int gx   = (int)gridDim.x;
  const int lin  = (int)blockIdx.y * gx + (int)blockIdx.x;
  const int l2gx = 31 - __clz(gx);
  const int g    = lin >> (3 + l2gx);
  const int rem  = lin & ((gx << 3) - 1);
  const int m0   = ((g << 3) + (rem & 7)) * 128;
  const int n0   = (rem >> 3) * 256;

  const int tid  = (int)threadIdx.x;
  const int lane = tid & 63, wid = tid >> 6;
  const int wm   = (wid >> 2) * 64;      // 2 M-halves of 128
  const int wn   = (wid & 3) * 64;       // 4 N-quarters of 256

  const u16* Az = Ab + (size_t)z * aBatch;
  const u16* Bz = BT + (size_t)z * bBatch;

  // ---- staging geometry (BK=32: 4 chunks of 8 elems per row)
  // A: 128 rows x 4 chunks = 512 slots = 1 gld/thread (bf16) or 8 floats (fp32)
  // B: 256 rows x 4 chunks = 1024 slots = 2 gld/thread
  const int rA  = tid >> 2, cA = tid & 3;
  const int cAs = cA ^ ((rA >> 1) & 3);                 // inverse swizzle
  u32 offA, offB[2], ldsOffA, ldsOffB[2];
  offA    = (u32)(((m0 + rA) * lda + cAs * 8) * 2);
  ldsOffA = (u32)(tid * 16);
  #pragma unroll
  for (int i = 0; i < 2; i++){
    int idx = tid + i * 512;
    int r = idx >> 2, c4 = idx & 3;
    int c4s = c4 ^ ((r >> 1) & 3);
    offB[i]    = (u32)(((n0 + r) * ldb + c4s * 8) * 2);
    ldsOffB[i] = (u32)(idx * 16);
  }

  auto stage = [&](int kt, int dbuf){
    const u32 kb = (u32)(kt * BK * 2);
    if (AMODE != 0){
      const u16* Asrc; u32 ka;
      if (AMODE == 2){
        Asrc = (kt * BK < 1024) ? Az : A2b;
        ka = (u32)(((kt * BK) & 1023) * 2);
      } else {
        Asrc = Az;
        ka = (u32)(kt * BK * 2);
      }
      gld_lds16((const char*)Asrc + offA + ka, (char*)&As[dbuf][0] + ldsOffA);
    }
    #pragma unroll
    for (int i = 0; i < 2; i++)
      gld_lds16((const char*)Bz + offB[i] + kb, (char*)&Bs[dbuf][0] + ldsOffB[i]);
  };

  // AMODE==0: fp32 A reg-staging (load early, cvt+ds_write late)
  v4f afr[2];
  auto loadA = [&](int kt){
    if (AMODE != 0) return;
    const float* src = Af + (size_t)(m0 + rA) * lda + kt * BK + cAs * 8;
    afr[0] = ((const v4f*)src)[0];
    afr[1] = ((const v4f*)src)[1];
  };
  auto writeA = [&](int dbuf){
    if (AMODE != 0) return;
    u32 q0 = (u32)f2bf(afr[0].x) | ((u32)f2bf(afr[0].y) << 16);
    u32 q1 = (u32)f2bf(afr[0].z) | ((u32)f2bf(afr[0].w) << 16);
    u32 q2 = (u32)f2bf(afr[1].x) | ((u32)f2bf(afr[1].y) << 16);
    u32 q3 = (u32)f2bf(afr[1].z) | ((u32)f2bf(afr[1].w) << 16);
    *(uint4*)((char*)&As[dbuf][0] + tid * 16) = make_uint4(q0, q1, q2, q3);
  };

  v4f acc[4][4];
  #pragma unroll
  for (int mi = 0; mi < 4; mi++)
    #pragma unroll
    for (int ni = 0; ni < 4; ni++)
      acc[mi][ni] = (v4f){0.f, 0.f, 0.f, 0.f};

  // read-side swizzle: phys chunk = lq ^ ((ll>>1)&3) -- per-lane constant
  // (base rows wm/wn + mi*16 are multiples of 16, so (row>>1)&3 == (ll>>1)&3)
  const int ll = lane & 15, lq = lane >> 4;
  const int ch = ((lq ^ ((ll >> 1) & 3)) << 3);        // elements within row

  // ---- prologue: stage slab 0 into buf 0
  if (AMODE == 0){ loadA(0); stage(0, 0); writeA(0); }
  else stage(0, 0);

  const int nt = K / BK;
  for (int kt = 0; kt < nt; kt++){
    const int buf = kt & 1;
    const bool pf = (kt + 1 < nt);

    // ---- single slab-top sync: drain ops issued a full slab ago, then BAR.
    asm volatile("s_waitcnt lgkmcnt(0)" ::: "memory");
    asm volatile("s_waitcnt vmcnt(0)" ::: "memory");
    __builtin_amdgcn_s_barrier();
    asm volatile("" ::: "memory");

    // ---- issue next slab's staging (full slab of flight time)
    if (pf){
      if (AMODE == 0) loadA(kt + 1);
      stage(kt + 1, buf ^ 1);
    }

    const u16* aB = &As[buf][(wm + ll) * 32] + ch;
    const u16* bB = &Bs[buf][(wn + ll) * 32] + ch;

    short8 a[4], b[4];
    #pragma unroll
    for (int mi = 0; mi < 4; mi++) a[mi] = *(const short8*)(aB + mi * 512);
    #pragma unroll
    for (int ni = 0; ni < 4; ni++) b[ni] = *(const short8*)(bB + ni * 512);

    __builtin_amdgcn_s_setprio(1);
    #pragma unroll
    for (int mi = 0; mi < 4; mi++)
      #pragma unroll
      for (int ni = 0; ni < 4; ni++)
        acc[mi][ni] = __builtin_amdgcn_mfma_f32_16x16x32_bf16(a[mi], b[ni], acc[mi][ni], 0, 0, 0);
    __builtin_amdgcn_s_setprio(0);

    if (pf) writeA(buf ^ 1);     // fp32 A cvt + ds_write late (AMODE==0)
  }

  // epilogue: C/D layout col = lane&15, row = (lane>>4)*4 + r (m89/m91)
  const int lr = lq * 4, lc = ll;
  if (EPI == 0 || EPI == 1){
    u16* C = (u16*)Cout + (size_t)z * cBatch;
    #pragma unroll
    for (int mi = 0; mi < 4; mi++){
      #pragma unroll
      for (int ni = 0; ni < 4; ni++){
        int col = n0 + wn + ni * 16 + lc;
        float bv = (EPI == 0) ? bias[col] : 0.f;
        #pragma unroll
        for (int r = 0; r < 4; r++){
          int row = m0 + wm + mi * 16 + lr + r;
          C[(size_t)row * ldc + col] = f2bf(acc[mi][ni][r] * scale + bv);
        }
      }
    }
  } else if (EPI == 3){
    u16* C = (u16*)Cout;
    #pragma unroll
    for (int mi = 0; mi < 4; mi++){
      int rowb = m0 + wm + mi * 16 + lr;        // multiple of 4, single batch
      int bb   = rowb >> 11;
      int rloc = rowb & 2047;
      #pragma unroll
      for (int ni = 0; ni < 4; ni++){
        int col = n0 + wn + ni * 16 + lc;
        float bv = bias[col];
        u32 pk0 = (u32)f2bf(acc[mi][ni][0] + bv) | ((u32)f2bf(acc[mi][ni][1] + bv) << 16);
        u32 pk1 = (u32)f2bf(acc[mi][ni][2] + bv) | ((u32)f2bf(acc[mi][ni][3] + bv) << 16);
        *(uint2*)&C[(size_t)bb * (1024ull * 2048) + (size_t)col * 2048 + rloc] =
            make_uint2(pk0, pk1);
      }
    }
  } else {
    float* C = (float*)Cout;
    #pragma unroll
    for (int mi = 0; mi < 4; mi++){
      #pragma unroll
      for (int ni = 0; ni < 4; ni++){
        int col = n0 + wn + ni * 16 + lc;
        float bv = bias[col];
        #pragma unroll
        for (int r = 0; r < 4; r++){
          int row = m0 + wm + mi * 16 + lr + r;
          float gg = acc[mi][ni][r] + bv;
          float sg = 1.f / (1.f + __expf(-gg));
          float xv = bf2f(xg[(size_t)row * 1024 + col]);
          C[(size_t)row * ldc + col] =
              xv * maskp[row] * sg + q0p[(size_t)row * 1024 + col];
        }
      }
    }
  }
}

// ---- 128x128x64 kernel kept for the small-workspace fallback path ----
template<int AMODE, int EPI>
__global__ __launch_bounds__(256) void gemm128(
    const float* __restrict__ Af,
    const u16* __restrict__ Ab,
    const u16* __restrict__ A2b,
    const u16* __restrict__ BT,
    int lda, int ldb, int K,
    void* __restrict__ Cout, int ldc,
    const float* __restrict__ bias, float scale,
    size_t aBatch, size_t bBatch, size_t cBatch,
    const u16* __restrict__ xg,
    const float* __restrict__ maskp,
    const float* __restrict__ q0p)
{
  constexpr int BM = 128, BN = 128, BK = 64;
  __shared__ __align__(16) u16 As[BM * BK];
  __shared__ __align__(16) u16 Bs[BN * BK];
  const int z   = blockIdx.z;
  const int lin  = blockIdx.y * gridDim.x + blockIdx.x;
  const int l2gx = 31 - __clz((int)gridDim.x);
  const int g    = lin >> (3 + l2gx);
  const int rem  = lin & (((int)gridDim.x << 3) - 1);
  const int m0   = ((g << 3) + (rem & 7)) * BM;
  const int n0   = (rem >> 3) * BN;
  const int tid = threadIdx.x;
  const int lane = tid & 63, wid = tid >> 6;
  const int wm = (wid >> 1) * 64, wn = (wid & 1) * 64;
  const u16* Abz = Ab + (size_t)z * aBatch;
  const u16* BTz = BT + (size_t)z * bBatch;

  v4f acc[4][4];
  #pragma unroll
  for (int mi = 0; mi < 4; mi++)
    #pragma unroll
    for (int ni = 0; ni < 4; ni++)
      acc[mi][ni] = (v4f){0.f, 0.f, 0.f, 0.f};

  for (int k0 = 0; k0 < K; k0 += BK){
    if (AMODE == 0){
      #pragma unroll
      for (int i = 0; i < 4; i++){
        int idx = tid + i * 256;
        int r = idx >> 3, s = idx & 7;
        const float* src = Af + (size_t)(m0 + r) * lda + (k0 + s * 8);
        v4f lo = ((const v4f*)src)[0];
        v4f hi = ((const v4f*)src)[1];
        u32 p0 = (u32)f2bf(lo.x) | ((u32)f2bf(lo.y) << 16);
        u32 p1 = (u32)f2bf(lo.z) | ((u32)f2bf(lo.w) << 16);
        u32 p2 = (u32)f2bf(hi.x) | ((u32)f2bf(hi.y) << 16);
        u32 p3 = (u32)f2bf(hi.z) | ((u32)f2bf(hi.w) << 16);
        *(uint4*)&As[(size_t)idx * 8] = make_uint4(p0, p1, p2, p3);
      }
    } else {
      #pragma unroll
      for (int i = 0; i < 4; i++){
        int idx = tid + i * 256;
        int r = idx >> 3, s = idx & 7;
        int kk = k0 + s * 8;
        const u16* src;
        if (AMODE == 2){
          src = (kk < 1024) ? (Abz + (size_t)(m0 + r) * 1024 + kk)
                            : (A2b + (size_t)(m0 + r) * 1024 + (kk - 1024));
        } else {
          src = Abz + (size_t)(m0 + r) * lda + kk;
        }
        gld_lds16(src, &As[(size_t)idx * 8]);
      }
    }
    #pragma unroll
    for (int i = 0; i < 4; i++){
      int idx = tid + i * 256;
      int r = idx >> 3, s = idx & 7;
      gld_lds16(BTz + (size_t)(n0 + r) * ldb + (k0 + s * 8), &Bs[(size_t)idx * 8]);
    }
    __syncthreads();
    #pragma unroll
    for (int ks = 0; ks < BK; ks += 32){
      short8 a[4], b[4];
      #pragma unroll
      for (int mi = 0; mi < 4; mi++)
        a[mi] = *(const short8*)&As[(wm + mi * 16 + (lane & 15)) * BK + ks + (lane >> 4) * 8];
      #pragma unroll
      for (int ni = 0; ni < 4; ni++)
        b[ni] = *(const short8*)&Bs[(wn + ni * 16 + (lane & 15)) * BK + ks + (lane >> 4) * 8];
      #pragma unroll
      for (int mi = 0; mi < 4; mi++)
        #pragma unroll
        for (int ni = 0; ni < 4; ni++)
          acc[mi][ni] = __builtin_amdgcn_mfma_f32_16x16x32_bf16(a[mi], b[ni], acc[mi][ni], 0, 0, 0);
    }
    __syncthreads();
  }

  const int lr = (lane >> 4) * 4, lc = lane & 15;
  if (EPI == 0 || EPI == 1){
    u16* C = (u16*)Cout + (size_t)z * cBatch;
    #pragma unroll
    for (int mi = 0; mi < 4; mi++){
      #pragma unroll
      for (int ni = 0; ni < 4; ni++){
        int col = n0 + wn + ni * 16 + lc;
        float bv = (EPI == 0) ? bias[col] : 0.f;
        #pragma unroll
        for (int r = 0; r < 4; r++){
          int row = m0 + wm + mi * 16 + lr + r;
          C[(size_t)row * ldc + col] = f2bf(acc[mi][ni][r] * scale + bv);
        }
      }
    }
  } else if (EPI == 3){
    u16* C = (u16*)Cout;
    #pragma unroll
    for (int mi = 0; mi < 4; mi++){
      int rowb = m0 + wm + mi * 16 + lr;
      int b    = rowb >> 11;
      int rloc = rowb & 2047;
      #pragma unroll
      for (int ni = 0; ni < 4; ni++){
        int col = n0 + wn + ni * 16 + lc;
        float bv = bias[col];
        u32 pk[2];
        pk[0] = (u32)f2bf(acc[mi][ni][0] + bv) | ((u32)f2bf(acc[mi][ni][1] + bv) << 16);
        pk[1] = (u32)f2bf(acc[mi][ni][2] + bv) | ((u32)f2bf(acc[mi][ni][3] + bv) << 16);
        *(uint2*)&C[(size_t)b * (1024ull * 2048) + (size_t)col * 2048 + rloc] =
            make_uint2(pk[0], pk[1]);
      }
    }
  } else {
    float* C = (float*)Cout;
    #pragma unroll
    for (int mi = 0; mi < 4; mi++){
      #pragma unroll
      for (int ni = 0; ni < 4; ni++){
        int col = n0 + wn + ni * 16 + lc;
        float bv = bias[col];
        #pragma unroll
        for (int r = 0; r < 4; r++){
          int row = m0 + wm + mi * 16 + lr + r;
          float g  = acc[mi][ni][r] + bv;
          float sg = 1.f / (1.f + __expf(-g));
          float xv = bf2f(xg[(size_t)row * 1024 + col]);
          C[(size_t)row * ldc + col] =
              xv * maskp[row] * sg + q0p[(size_t)row * 1024 + col];
        }
      }
    }
  }
}

// ---------------------------------------------------------------------------
// B=8, L=2048, D=1024. All inputs fp32. Pipeline (bigws):
//   1. Wq/Wk/Wv/Wg -> bf16 transposed ([N][K]) in ws
//   2. projections read fp32 q/k/v directly (AMODE=0, no cvt pass);
//      V proj stores TRANSPOSED -> vpT [b][d][l]
//   3. per chunk: S = qp kp^T /32 ; softmax ; x = P V
//   4. gate GEMM over concat(qp,x) with fused sigmoid/mask/residual epilogue
// All big GEMMs: 128x256x32 tiles, 48KB LDS -> 3 blocks/CU, grids >= 512.
// ---------------------------------------------------------------------------
extern "C" void kernel_launch(void* const* d_in, const int* in_sizes, int n_in,
                              void* d_out, int out_size, void* d_ws, size_t ws_size,
                              hipStream_t stream)
{
  const float* q    = (const float*)d_in[0];
  const float* k    = (const float*)d_in[1];
  const float* v    = (const float*)d_in[2];
  const float* mask = (const float*)d_in[3];
  const float* Wq   = (const float*)d_in[4];
  const float* bq   = (const float*)d_in[5];
  const float* Wk   = (const float*)d_in[6];
  const float* bk   = (const float*)d_in[7];
  const float* Wv   = (const float*)d_in[8];
  const float* bv   = (const float*)d_in[9];
  const float* Wg   = (const float*)d_in[10];
  const float* bg   = (const float*)d_in[11];
  float* out = (float*)d_out;

  char* ws = (char*)d_ws;
  const size_t MB = 1024ull * 1024ull;
  u16* WqT = (u16*)(ws + 0 * MB);    // [1024][1024] bf16
  u16* WkT = (u16*)(ws + 2 * MB);
  u16* WvT = (u16*)(ws + 4 * MB);
  u16* WgT = (u16*)(ws + 6 * MB);    // [1024][2048] bf16
  u16* qp  = (u16*)(ws + 10 * MB);   // [16384][1024] bf16
  u16* kp  = (u16*)(ws + 42 * MB);   // [16384][1024] bf16 ; x overlays per batch
  u16* vpT = (u16*)(ws + 74 * MB);   // [8][1024][2048] bf16 (V proj, transposed)
  u16* S   = (u16*)(ws + 106 * MB);  // [nb][2048][2048] bf16, reused per chunk
  u16* x   = kp;

  const bool bigws = ws_size >= 138 * MB;
  int nb = 8;
  while (nb > 1 && 106 * MB + (size_t)nb * 8 * MB > ws_size) nb >>= 1;
  const int nchunks = 8 / nb;

  dim3 B(256);
  dim3 T5(512);

  // 1. weights -> bf16, transposed to [N][K]
  transpose_w_bf16<<<dim3(16, 16, 1), B, 0, stream>>>(Wq, WqT, 1024, 1024);
  transpose_w_bf16<<<dim3(16, 16, 1), B, 0, stream>>>(Wk, WkT, 1024, 1024);
  transpose_w_bf16<<<dim3(16, 16, 1), B, 0, stream>>>(Wv, WvT, 1024, 1024);
  transpose_w_bf16<<<dim3(32, 16, 1), B, 0, stream>>>(Wg, WgT, 2048, 1024);

  if (bigws){
    // 2. projections: [16384,1024] x [1024,1024], fp32 A direct
    //    grid (n-tiles=4, m-tiles=128) = 512 blocks
    gemm256<0, 0><<<dim3(4, 128, 1), T5, 0, stream>>>(q, nullptr, nullptr, WqT,
        1024, 1024, 1024, qp, 1024, bq, 1.f, 0, 0, 0, nullptr, nullptr, nullptr);
    gemm256<0, 0><<<dim3(4, 128, 1), T5, 0, stream>>>(k, nullptr, nullptr, WkT,
        1024, 1024, 1024, kp, 1024, bk, 1.f, 0, 0, 0, nullptr, nullptr, nullptr);
    gemm256<0, 3><<<dim3(4, 128, 1), T5, 0, stream>>>(v, nullptr, nullptr, WvT,
        1024, 1024, 1024, vpT, 0, bv, 1.f, 0, 0, 0, nullptr, nullptr, nullptr);

    // 3. attention middle, nb batches at a time
    for (int c = 0; c < nchunks; c++){
      const size_t boff = (size_t)c * nb;
      // scores: m-tiles 16, n-tiles 8 -> (8,16,nb) = 128*nb blocks
      gemm256<1, 1><<<dim3(8, 16, nb), T5, 0, stream>>>(nullptr,
          qp + boff * 2048 * 1024, nullptr, kp + boff * 2048 * 1024,
          1024, 1024, 1024, S, 2048, nullptr, 0.03125f,
          2048ull * 1024, 2048ull * 1024, 2048ull * 2048, nullptr, nullptr, nullptr);
      softmax_rows<<<dim3(nb * 512, 1, 1), B, 0, stream>>>(S);
      // PV: m-tiles 16, n-tiles 4 -> (4,16,nb) = 64*nb blocks
      gemm256<1, 1><<<dim3(4, 16, nb), T5, 0, stream>>>(nullptr,
          S, nullptr, vpT + boff * 1024 * 2048,
          2048, 2048, 2048, x + boff * 2048 * 1024, 1024, nullptr, 1.f,
          2048ull * 2048, 1024ull * 2048, 2048ull * 1024, nullptr, nullptr, nullptr);
    }

    // 4. gate GEMM over concat(qp, x) + fused epilogue -> fp32 out
    gemm256<2, 2><<<dim3(4, 128, 1), T5, 0, stream>>>(nullptr, qp, x, WgT,
        1024, 2048, 2048, out, 1024, bg, 1.f, 0, 0, 0, x, mask, q);
  } else {
    // fallback: original 128^2 pipeline with fp32 staging projections
    gemm128<0, 0><<<dim3(8, 128, 1), B, 0, stream>>>(q, nullptr, nullptr, WqT,
        1024, 1024, 1024, qp, 1024, bq, 1.f, 0, 0, 0, nullptr, nullptr, nullptr);
    gemm128<0, 0><<<dim3(8, 128, 1), B, 0, stream>>>(k, nullptr, nullptr, WkT,
        1024, 1024, 1024, kp, 1024, bk, 1.f, 0, 0, 0, nullptr, nullptr, nullptr);
    gemm128<0, 3><<<dim3(8, 128, 1), B, 0, stream>>>(v, nullptr, nullptr, WvT,
        1024, 1024, 1024, vpT, 0, bv, 1.f, 0, 0, 0, nullptr, nullptr, nullptr);

    for (int c = 0; c < nchunks; c++){
      const size_t boff = (size_t)c * nb;
      gemm128<1, 1><<<dim3(16, 16, nb), B, 0, stream>>>(nullptr,
          qp + boff * 2048 * 1024, nullptr, kp + boff * 2048 * 1024,
          1024, 1024, 1024, S, 2048, nullptr, 0.03125f,
          2048ull * 1024, 2048ull * 1024, 2048ull * 2048, nullptr, nullptr, nullptr);
      softmax_rows<<<dim3(nb * 512, 1, 1), B, 0, stream>>>(S);
      gemm128<1, 1><<<dim3(8, 16, nb), B, 0, stream>>>(nullptr,
          S, nullptr, vpT + boff * 1024 * 2048,
          2048, 2048, 2048, x + boff * 2048 * 1024, 1024, nullptr, 1.f,
          2048ull * 2048, 1024ull * 2048, 2048ull * 1024, nullptr, nullptr, nullptr);
    }

    gemm128<2, 2><<<dim3(8, 128, 1), B, 0, stream>>>(nullptr, qp, x, WgT,
        1024, 2048, 2048, out, 1024, bg, 1.f, 0, 0, 0, x, mask, q);
  }
}

// Round 6
// 652.938 us; speedup vs baseline: 4.5421x; 4.5421x over previous
//
#include <hip/hip_runtime.h>

typedef unsigned int u32;
typedef unsigned short u16;
using v4f    = __attribute__((ext_vector_type(4))) float;
using short8 = __attribute__((ext_vector_type(8))) short;

#define GAS __attribute__((address_space(1)))
#define LAS __attribute__((address_space(3)))

// ---- bf16 helpers (RNE, matches HW convert; inputs are finite) ----
__device__ __forceinline__ u16 f2bf(float f){
  u32 u = __builtin_bit_cast(u32, f);
  u32 r = (u + 0x7fffu + ((u >> 16) & 1u)) >> 16;
  return (u16)r;
}
__device__ __forceinline__ float bf2f(u16 h){
  u32 u = ((u32)h) << 16;
  return __builtin_bit_cast(float, u);
}

// async global->LDS, 16B per lane. LDS dest must be wave-uniform base + lane*16.
__device__ __forceinline__ void gld_lds16(const void* g, void* l){
  __builtin_amdgcn_global_load_lds((const GAS u32*)g, (LAS u32*)l, 16, 0, 0);
}

// ---- transpose fp32 [K][N] -> bf16 [N][K] (weights only) ----
__global__ __launch_bounds__(256) void transpose_w_bf16(
    const float* __restrict__ in, u16* __restrict__ out, int K, int N)
{
  __shared__ float t[64][65];
  const int k0 = blockIdx.x * 64, n0 = blockIdx.y * 64;
  const int tx = threadIdx.x & 63, ty = threadIdx.x >> 6;
  #pragma unroll
  for (int i = 0; i < 16; i++){
    int r = ty + i * 4;
    t[r][tx] = in[(size_t)(k0 + r) * N + (n0 + tx)];
  }
  __syncthreads();
  #pragma unroll
  for (int i = 0; i < 16; i++){
    int r = ty + i * 4;
    out[(size_t)(n0 + r) * K + (k0 + tx)] = f2bf(t[tx][r]);
  }
}

// ---- in-place softmax, one WAVE per 2048-elem row (4 rows/block) ----
__global__ __launch_bounds__(256) void softmax_rows(u16* __restrict__ S){
  const int lane = threadIdx.x & 63, wid = threadIdx.x >> 6;
  u16* p = S + ((size_t)blockIdx.x * 4 + wid) * 2048;
  uint4 u[4];
  #pragma unroll
  for (int j = 0; j < 4; j++) u[j] = ((const uint4*)p)[lane + j * 64];
  float f[32];
  #pragma unroll
  for (int j = 0; j < 4; j++){
    u32 w4[4] = {u[j].x, u[j].y, u[j].z, u[j].w};
    #pragma unroll
    for (int i = 0; i < 4; i++){
      f[j * 8 + 2*i]     = bf2f((u16)(w4[i] & 0xffffu));
      f[j * 8 + 2*i + 1] = bf2f((u16)(w4[i] >> 16));
    }
  }
  float m = f[0];
  #pragma unroll
  for (int i = 1; i < 32; i++) m = fmaxf(m, f[i]);
  #pragma unroll
  for (int o = 32; o >= 1; o >>= 1) m = fmaxf(m, __shfl_xor(m, o));
  float s = 0.f;
  #pragma unroll
  for (int i = 0; i < 32; i++){ f[i] = __expf(f[i] - m); s += f[i]; }
  #pragma unroll
  for (int o = 32; o >= 1; o >>= 1) s += __shfl_xor(s, o);
  const float inv = 1.f / s;
  #pragma unroll
  for (int j = 0; j < 4; j++){
    u32 w4[4];
    #pragma unroll
    for (int i = 0; i < 4; i++)
      w4[i] = (u32)f2bf(f[j * 8 + 2*i] * inv) |
              ((u32)f2bf(f[j * 8 + 2*i + 1] * inv) << 16);
    ((uint4*)p)[lane + j * 64] = make_uint4(w4[0], w4[1], w4[2], w4[3]);
  }
}

// ===========================================================================
// 256x128x32 bf16 GEMM, occupancy-first: 48 KiB LDS double-buffer -> 2-3
//   blocks/CU co-resident. NO launch_bounds min-waves arg (r5 post-mortem:
//   forcing 6 waves/EU squeezed the allocator -> acc spilled to scratch,
//   1.3 GB scratch writes; r4's plain (512) gave 104 VGPR, no spill).
//   Body = r4's measured-best free-flow: single tile-top
//   {lgkmcnt0 + vmcnt0 + barrier}, stage next slab early, ds_read + MFMA
//   free-flow with setprio. Cross-block overlap fills the drain bubbles
//   (m114) that single-block schedule variants could not.
//   512 threads = 8 waves (4M x 2N), per-wave output 64x64 (acc[4][4]).
// LDS swizzle (BK=32, 64B rows): slot (r,c4) holds global k-chunk
//   c4 ^ ((r>>1)&3); reads apply the same XOR (involution, r5-refcheck'd).
//   2-way bank aliasing only (free, m136).
// AMODE: 0 = A fp32 global, reg-staged (load early / cvt+ds_write late)
//        1 = A bf16 via global_load_lds
//        2 = A concat(qp,x) bf16 (K split at 1024; 32|1024 -> wave-uniform)
// EPI:   0 = +bias, bf16   1 = *scale, bf16   2 = gate-fused, fp32
//        3 = +bias, bf16 TRANSPOSED [batch][col][rowlocal]
// Grid: gridDim.x = n-tiles (pow2), gridDim.y = m-tiles (mult of 8);
//   GROUP-8: 8 consecutive blocks share a B-panel, walk 8 A-panels.
// ===========================================================================
template<int AMODE, int EPI>
__global__ __launch_bounds__(512) void gemm256(
    const float* __restrict__ Af,
    const u16* __restrict__ Ab,
    const u16* __restrict__ A2b,
    const u16* __restrict__ BT,
    int lda, int ldb, int K,
    void* __restrict__ Cout, int ldc,
    const float* __restrict__ bias, float scale,
    size_t aBatch, size_t bBatch, size_t cBatch,
    const u16* __restrict__ xg,
    const float* __restrict__ maskp,
    const float* __restrict__ q0p)
{
  constexpr int BK = 32;
  __shared__ __align__(16) u16 As[2][256 * 32];   // [buf][r*32 + c4*8 + e] 32KB
  __shared__ __align__(16) u16 Bs[2][128 * 32];   //                        16KB

  const int z   = blockIdx.z;
  const int gx   = (int)gridDim.x;
  const int lin  = (int)blockIdx.y * gx + (int)blockIdx.x;
  const int l2gx = 31 - __clz(gx);
  const int g    = lin >> (3 + l2gx);
  const int rem  = lin & ((gx << 3) - 1);
  const int m0   = ((g << 3) + (rem & 7)) * 256;
  const int n0   = (rem >> 3) * 128;

  const int tid  = (int)threadIdx.x;
  const int lane = tid & 63, wid = tid >> 6;
  const int wm   = (wid >> 1) * 64;      // 4 M-quarters of 256
  const int wn   = (wid & 1) * 64;       // 2 N-halves of 128

  const u16* Az = Ab + (size_t)z * aBatch;
  const u16* Bz = BT + (size_t)z * bBatch;

  // ---- staging geometry (BK=32: 4 chunks of 8 elems per row)
  // A: 256 rows x 4 chunks = 1024 slots = 2 gld/thread
  // B: 128 rows x 4 chunks =  512 slots = 1 gld/thread
  u32 offA[2], ldsOffA[2], offB, ldsOffB;
  #pragma unroll
  for (int i = 0; i < 2; i++){
    int idx = tid + i * 512;
    int r = idx >> 2, c4 = idx & 3;
    int c4s = c4 ^ ((r >> 1) & 3);                     // inverse swizzle
    offA[i]    = (u32)(((m0 + r) * lda + c4s * 8) * 2);
    ldsOffA[i] = (u32)(idx * 16);
  }
  {
    const int rB  = tid >> 2, cB = tid & 3;
    const int cBs = cB ^ ((rB >> 1) & 3);
    offB    = (u32)(((n0 + rB) * ldb + cBs * 8) * 2);
    ldsOffB = (u32)(tid * 16);
  }

  auto stage = [&](int kt, int dbuf){
    const u32 kb = (u32)(kt * BK * 2);
    if (AMODE != 0){
      const u16* Asrc; u32 ka;
      if (AMODE == 2){
        Asrc = (kt * BK < 1024) ? Az : A2b;
        ka = (u32)(((kt * BK) & 1023) * 2);
      } else {
        Asrc = Az;
        ka = (u32)(kt * BK * 2);
      }
      #pragma unroll
      for (int i = 0; i < 2; i++)
        gld_lds16((const char*)Asrc + offA[i] + ka, (char*)&As[dbuf][0] + ldsOffA[i]);
    }
    gld_lds16((const char*)Bz + offB + kb, (char*)&Bs[dbuf][0] + ldsOffB);
  };

  // AMODE==0: fp32 A reg-staging (load early, cvt+ds_write late)
  v4f afr[2][2];
  auto loadA = [&](int kt){
    if (AMODE != 0) return;
    #pragma unroll
    for (int i = 0; i < 2; i++){
      int idx = tid + i * 512;
      int r = idx >> 2, c4s = (idx & 3) ^ ((r >> 1) & 3);
      const float* src = Af + (size_t)(m0 + r) * lda + kt * BK + c4s * 8;
      afr[i][0] = ((const v4f*)src)[0];
      afr[i][1] = ((const v4f*)src)[1];
    }
  };
  auto writeA = [&](int dbuf){
    if (AMODE != 0) return;
    #pragma unroll
    for (int i = 0; i < 2; i++){
      int idx = tid + i * 512;
      u32 q0 = (u32)f2bf(afr[i][0].x) | ((u32)f2bf(afr[i][0].y) << 16);
      u32 q1 = (u32)f2bf(afr[i][0].z) | ((u32)f2bf(afr[i][0].w) << 16);
      u32 q2 = (u32)f2bf(afr[i][1].x) | ((u32)f2bf(afr[i][1].y) << 16);
      u32 q3 = (u32)f2bf(afr[i][1].z) | ((u32)f2bf(afr[i][1].w) << 16);
      *(uint4*)((char*)&As[dbuf][0] + idx * 16) = make_uint4(q0, q1, q2, q3);
    }
  };

  v4f acc[4][4];
  #pragma unroll
  for (int mi = 0; mi < 4; mi++)
    #pragma unroll
    for (int ni = 0; ni < 4; ni++)
      acc[mi][ni] = (v4f){0.f, 0.f, 0.f, 0.f};

  // read-side swizzle: phys chunk = lq ^ ((ll>>1)&3) -- per-lane constant
  // (frag base rows are multiples of 16, so (row>>1)&3 == (ll>>1)&3)
  const int ll = lane & 15, lq = lane >> 4;
  const int ch = ((lq ^ ((ll >> 1) & 3)) << 3);        // elements within row

  // ---- prologue: stage slab 0 into buf 0
  if (AMODE == 0){ loadA(0); stage(0, 0); writeA(0); }
  else stage(0, 0);

  const int nt = K / BK;
  for (int kt = 0; kt < nt; kt++){
    const int buf = kt & 1;
    const bool pf = (kt + 1 < nt);

    // ---- single slab-top sync: drain ops issued a full slab ago, then BAR.
    asm volatile("s_waitcnt lgkmcnt(0)" ::: "memory");
    asm volatile("s_waitcnt vmcnt(0)" ::: "memory");
    __builtin_amdgcn_s_barrier();
    asm volatile("" ::: "memory");

    // ---- issue next slab's staging (full slab of flight time)
    if (pf){
      if (AMODE == 0) loadA(kt + 1);
      stage(kt + 1, buf ^ 1);
    }

    const u16* aB = &As[buf][(wm + ll) * 32] + ch;
    const u16* bB = &Bs[buf][(wn + ll) * 32] + ch;

    short8 a[4], b[4];
    #pragma unroll
    for (int mi = 0; mi < 4; mi++) a[mi] = *(const short8*)(aB + mi * 512);
    #pragma unroll
    for (int ni = 0; ni < 4; ni++) b[ni] = *(const short8*)(bB + ni * 512);

    __builtin_amdgcn_s_setprio(1);
    #pragma unroll
    for (int mi = 0; mi < 4; mi++)
      #pragma unroll
      for (int ni = 0; ni < 4; ni++)
        acc[mi][ni] = __builtin_amdgcn_mfma_f32_16x16x32_bf16(a[mi], b[ni], acc[mi][ni], 0, 0, 0);
    __builtin_amdgcn_s_setprio(0);

    if (pf) writeA(buf ^ 1);     // fp32 A cvt + ds_write late (AMODE==0)
  }

  // epilogue: C/D layout col = lane&15, row = (lane>>4)*4 + r (m89/m91)
  const int lr = lq * 4, lc = ll;
  if (EPI == 0 || EPI == 1){
    u16* C = (u16*)Cout + (size_t)z * cBatch;
    #pragma unroll
    for (int mi = 0; mi < 4; mi++){
      #pragma unroll
      for (int ni = 0; ni < 4; ni++){
        int col = n0 + wn + ni * 16 + lc;
        float bv = (EPI == 0) ? bias[col] : 0.f;
        #pragma unroll
        for (int r = 0; r < 4; r++){
          int row = m0 + wm + mi * 16 + lr + r;
          C[(size_t)row * ldc + col] = f2bf(acc[mi][ni][r] * scale + bv);
        }
      }
    }
  } else if (EPI == 3){
    u16* C = (u16*)Cout;
    #pragma unroll
    for (int mi = 0; mi < 4; mi++){
      int rowb = m0 + wm + mi * 16 + lr;        // multiple of 4, single batch
      int bb   = rowb >> 11;
      int rloc = rowb & 2047;
      #pragma unroll
      for (int ni = 0; ni < 4; ni++){
        int col = n0 + wn + ni * 16 + lc;
        float bv = bias[col];
        u32 pk0 = (u32)f2bf(acc[mi][ni][0] + bv) | ((u32)f2bf(acc[mi][ni][1] + bv) << 16);
        u32 pk1 = (u32)f2bf(acc[mi][ni][2] + bv) | ((u32)f2bf(acc[mi][ni][3] + bv) << 16);
        *(uint2*)&C[(size_t)bb * (1024ull * 2048) + (size_t)col * 2048 + rloc] =
            make_uint2(pk0, pk1);
      }
    }
  } else {
    float* C = (float*)Cout;
    #pragma unroll
    for (int mi = 0; mi < 4; mi++){
      #pragma unroll
      for (int ni = 0; ni < 4; ni++){
        int col = n0 + wn + ni * 16 + lc;
        float bv = bias[col];
        #pragma unroll
        for (int r = 0; r < 4; r++){
          int row = m0 + wm + mi * 16 + lr + r;
          float gg = acc[mi][ni][r] + bv;
          float sg = 1.f / (1.f + __expf(-gg));
          float xv = bf2f(xg[(size_t)row * 1024 + col]);
          C[(size_t)row * ldc + col] =
              xv * maskp[row] * sg + q0p[(size_t)row * 1024 + col];
        }
      }
    }
  }
}

// ---- 128x128x64 kernel kept for the small-workspace fallback path ----
template<int AMODE, int EPI>
__global__ __launch_bounds__(256) void gemm128(
    const float* __restrict__ Af,
    const u16* __restrict__ Ab,
    const u16* __restrict__ A2b,
    const u16* __restrict__ BT,
    int lda, int ldb, int K,
    void* __restrict__ Cout, int ldc,
    const float* __restrict__ bias, float scale,
    size_t aBatch, size_t bBatch, size_t cBatch,
    const u16* __restrict__ xg,
    const float* __restrict__ maskp,
    const float* __restrict__ q0p)
{
  constexpr int BM = 128, BN = 128, BK = 64;
  __shared__ __align__(16) u16 As[BM * BK];
  __shared__ __align__(16) u16 Bs[BN * BK];
  const int z   = blockIdx.z;
  const int lin  = blockIdx.y * gridDim.x + blockIdx.x;
  const int l2gx = 31 - __clz((int)gridDim.x);
  const int g    = lin >> (3 + l2gx);
  const int rem  = lin & (((int)gridDim.x << 3) - 1);
  const int m0   = ((g << 3) + (rem & 7)) * BM;
  const int n0   = (rem >> 3) * BN;
  const int tid = threadIdx.x;
  const int lane = tid & 63, wid = tid >> 6;
  const int wm = (wid >> 1) * 64, wn = (wid & 1) * 64;
  const u16* Abz = Ab + (size_t)z * aBatch;
  const u16* BTz = BT + (size_t)z * bBatch;

  v4f acc[4][4];
  #pragma unroll
  for (int mi = 0; mi < 4; mi++)
    #pragma unroll
    for (int ni = 0; ni < 4; ni++)
      acc[mi][ni] = (v4f){0.f, 0.f, 0.f, 0.f};

  for (int k0 = 0; k0 < K; k0 += BK){
    if (AMODE == 0){
      #pragma unroll
      for (int i = 0; i < 4; i++){
        int idx = tid + i * 256;
        int r = idx >> 3, s = idx & 7;
        const float* src = Af + (size_t)(m0 + r) * lda + (k0 + s * 8);
        v4f lo = ((const v4f*)src)[0];
        v4f hi = ((const v4f*)src)[1];
        u32 p0 = (u32)f2bf(lo.x) | ((u32)f2bf(lo.y) << 16);
        u32 p1 = (u32)f2bf(lo.z) | ((u32)f2bf(lo.w) << 16);
        u32 p2 = (u32)f2bf(hi.x) | ((u32)f2bf(hi.y) << 16);
        u32 p3 = (u32)f2bf(hi.z) | ((u32)f2bf(hi.w) << 16);
        *(uint4*)&As[(size_t)idx * 8] = make_uint4(p0, p1, p2, p3);
      }
    } else {
      #pragma unroll
      for (int i = 0; i < 4; i++){
        int idx = tid + i * 256;
        int r = idx >> 3, s = idx & 7;
        int kk = k0 + s * 8;
        const u16* src;
        if (AMODE == 2){
          src = (kk < 1024) ? (Abz + (size_t)(m0 + r) * 1024 + kk)
                            : (A2b + (size_t)(m0 + r) * 1024 + (kk - 1024));
        } else {
          src = Abz + (size_t)(m0 + r) * lda + kk;
        }
        gld_lds16(src, &As[(size_t)idx * 8]);
      }
    }
    #pragma unroll
    for (int i = 0; i < 4; i++){
      int idx = tid + i * 256;
      int r = idx >> 3, s = idx & 7;
      gld_lds16(BTz + (size_t)(n0 + r) * ldb + (k0 + s * 8), &Bs[(size_t)idx * 8]);
    }
    __syncthreads();
    #pragma unroll
    for (int ks = 0; ks < BK; ks += 32){
      short8 a[4], b[4];
      #pragma unroll
      for (int mi = 0; mi < 4; mi++)
        a[mi] = *(const short8*)&As[(wm + mi * 16 + (lane & 15)) * BK + ks + (lane >> 4) * 8];
      #pragma unroll
      for (int ni = 0; ni < 4; ni++)
        b[ni] = *(const short8*)&Bs[(wn + ni * 16 + (lane & 15)) * BK + ks + (lane >> 4) * 8];
      #pragma unroll
      for (int mi = 0; mi < 4; mi++)
        #pragma unroll
        for (int ni = 0; ni < 4; ni++)
          acc[mi][ni] = __builtin_amdgcn_mfma_f32_16x16x32_bf16(a[mi], b[ni], acc[mi][ni], 0, 0, 0);
    }
    __syncthreads();
  }

  const int lr = (lane >> 4) * 4, lc = lane & 15;
  if (EPI == 0 || EPI == 1){
    u16* C = (u16*)Cout + (size_t)z * cBatch;
    #pragma unroll
    for (int mi = 0; mi < 4; mi++){
      #pragma unroll
      for (int ni = 0; ni < 4; ni++){
        int col = n0 + wn + ni * 16 + lc;
        float bv = (EPI == 0) ? bias[col] : 0.f;
        #pragma unroll
        for (int r = 0; r < 4; r++){
          int row = m0 + wm + mi * 16 + lr + r;
          C[(size_t)row * ldc + col] = f2bf(acc[mi][ni][r] * scale + bv);
        }
      }
    }
  } else if (EPI == 3){
    u16* C = (u16*)Cout;
    #pragma unroll
    for (int mi = 0; mi < 4; mi++){
      int rowb = m0 + wm + mi * 16 + lr;
      int b    = rowb >> 11;
      int rloc = rowb & 2047;
      #pragma unroll
      for (int ni = 0; ni < 4; ni++){
        int col = n0 + wn + ni * 16 + lc;
        float bv = bias[col];
        u32 pk[2];
        pk[0] = (u32)f2bf(acc[mi][ni][0] + bv) | ((u32)f2bf(acc[mi][ni][1] + bv) << 16);
        pk[1] = (u32)f2bf(acc[mi][ni][2] + bv) | ((u32)f2bf(acc[mi][ni][3] + bv) << 16);
        *(uint2*)&C[(size_t)b * (1024ull * 2048) + (size_t)col * 2048 + rloc] =
            make_uint2(pk[0], pk[1]);
      }
    }
  } else {
    float* C = (float*)Cout;
    #pragma unroll
    for (int mi = 0; mi < 4; mi++){
      #pragma unroll
      for (int ni = 0; ni < 4; ni++){
        int col = n0 + wn + ni * 16 + lc;
        float bv = bias[col];
        #pragma unroll
        for (int r = 0; r < 4; r++){
          int row = m0 + wm + mi * 16 + lr + r;
          float g  = acc[mi][ni][r] + bv;
          float sg = 1.f / (1.f + __expf(-g));
          float xv = bf2f(xg[(size_t)row * 1024 + col]);
          C[(size_t)row * ldc + col] =
              xv * maskp[row] * sg + q0p[(size_t)row * 1024 + col];
        }
      }
    }
  }
}

// ---------------------------------------------------------------------------
// B=8, L=2048, D=1024. All inputs fp32. Pipeline (bigws):
//   1. Wq/Wk/Wv/Wg -> bf16 transposed ([N][K]) in ws
//   2. projections read fp32 q/k/v directly (AMODE=0, no cvt pass);
//      V proj stores TRANSPOSED -> vpT [b][d][l]
//   3. per chunk: S = qp kp^T /32 ; softmax ; x = P V
//   4. gate GEMM over concat(qp,x) with fused sigmoid/mask/residual epilogue
// All big GEMMs: 256x128x32 tiles, 48KB LDS -> 2-3 blocks/CU, grids >= 512.
// ---------------------------------------------------------------------------
extern "C" void kernel_launch(void* const* d_in, const int* in_sizes, int n_in,
                              void* d_out, int out_size, void* d_ws, size_t ws_size,
                              hipStream_t stream)
{
  const float* q    = (const float*)d_in[0];
  const float* k    = (const float*)d_in[1];
  const float* v    = (const float*)d_in[2];
  const float* mask = (const float*)d_in[3];
  const float* Wq   = (const float*)d_in[4];
  const float* bq   = (const float*)d_in[5];
  const float* Wk   = (const float*)d_in[6];
  const float* bk   = (const float*)d_in[7];
  const float* Wv   = (const float*)d_in[8];
  const float* bv   = (const float*)d_in[9];
  const float* Wg   = (const float*)d_in[10];
  const float* bg   = (const float*)d_in[11];
  float* out = (float*)d_out;

  char* ws = (char*)d_ws;
  const size_t MB = 1024ull * 1024ull;
  u16* WqT = (u16*)(ws + 0 * MB);    // [1024][1024] bf16
  u16* WkT = (u16*)(ws + 2 * MB);
  u16* WvT = (u16*)(ws + 4 * MB);
  u16* WgT = (u16*)(ws + 6 * MB);    // [1024][2048] bf16
  u16* qp  = (u16*)(ws + 10 * MB);   // [16384][1024] bf16
  u16* kp  = (u16*)(ws + 42 * MB);   // [16384][1024] bf16 ; x overlays per batch
  u16* vpT = (u16*)(ws + 74 * MB);   // [8][1024][2048] bf16 (V proj, transposed)
  u16* S   = (u16*)(ws + 106 * MB);  // [nb][2048][2048] bf16, reused per chunk
  u16* x   = kp;

  const bool bigws = ws_size >= 138 * MB;
  int nb = 8;
  while (nb > 1 && 106 * MB + (size_t)nb * 8 * MB > ws_size) nb >>= 1;
  const int nchunks = 8 / nb;

  dim3 B(256);
  dim3 T5(512);

  // 1. weights -> bf16, transposed to [N][K]
  transpose_w_bf16<<<dim3(16, 16, 1), B, 0, stream>>>(Wq, WqT, 1024, 1024);
  transpose_w_bf16<<<dim3(16, 16, 1), B, 0, stream>>>(Wk, WkT, 1024, 1024);
  transpose_w_bf16<<<dim3(16, 16, 1), B, 0, stream>>>(Wv, WvT, 1024, 1024);
  transpose_w_bf16<<<dim3(32, 16, 1), B, 0, stream>>>(Wg, WgT, 2048, 1024);

  if (bigws){
    // 2. projections: [16384,1024] x [1024,1024], fp32 A direct
    //    grid (n-tiles=8, m-tiles=64) = 512 blocks
    gemm256<0, 0><<<dim3(8, 64, 1), T5, 0, stream>>>(q, nullptr, nullptr, WqT,
        1024, 1024, 1024, qp, 1024, bq, 1.f, 0, 0, 0, nullptr, nullptr, nullptr);
    gemm256<0, 0><<<dim3(8, 64, 1), T5, 0, stream>>>(k, nullptr, nullptr, WkT,
        1024, 1024, 1024, kp, 1024, bk, 1.f, 0, 0, 0, nullptr, nullptr, nullptr);
    gemm256<0, 3><<<dim3(8, 64, 1), T5, 0, stream>>>(v, nullptr, nullptr, WvT,
        1024, 1024, 1024, vpT, 0, bv, 1.f, 0, 0, 0, nullptr, nullptr, nullptr);

    // 3. attention middle, nb batches at a time
    for (int c = 0; c < nchunks; c++){
      const size_t boff = (size_t)c * nb;
      // scores: n-tiles 16, m-tiles 8 -> (16,8,nb)
      gemm256<1, 1><<<dim3(16, 8, nb), T5, 0, stream>>>(nullptr,
          qp + boff * 2048 * 1024, nullptr, kp + boff * 2048 * 1024,
          1024, 1024, 1024, S, 2048, nullptr, 0.03125f,
          2048ull * 1024, 2048ull * 1024, 2048ull * 2048, nullptr, nullptr, nullptr);
      softmax_rows<<<dim3(nb * 512, 1, 1), B, 0, stream>>>(S);
      // PV: n-tiles 8, m-tiles 8 -> (8,8,nb)
      gemm256<1, 1><<<dim3(8, 8, nb), T5, 0, stream>>>(nullptr,
          S, nullptr, vpT + boff * 1024 * 2048,
          2048, 2048, 2048, x + boff * 2048 * 1024, 1024, nullptr, 1.f,
          2048ull * 2048, 1024ull * 2048, 2048ull * 1024, nullptr, nullptr, nullptr);
    }

    // 4. gate GEMM over concat(qp, x) + fused epilogue -> fp32 out
    gemm256<2, 2><<<dim3(8, 64, 1), T5, 0, stream>>>(nullptr, qp, x, WgT,
        1024, 2048, 2048, out, 1024, bg, 1.f, 0, 0, 0, x, mask, q);
  } else {
    // fallback: original 128^2 pipeline with fp32 staging projections
    gemm128<0, 0><<<dim3(8, 128, 1), B, 0, stream>>>(q, nullptr, nullptr, WqT,
        1024, 1024, 1024, qp, 1024, bq, 1.f, 0, 0, 0, nullptr, nullptr, nullptr);
    gemm128<0, 0><<<dim3(8, 128, 1), B, 0, stream>>>(k, nullptr, nullptr, WkT,
        1024, 1024, 1024, kp, 1024, bk, 1.f, 0, 0, 0, nullptr, nullptr, nullptr);
    gemm128<0, 3><<<dim3(8, 128, 1), B, 0, stream>>>(v, nullptr, nullptr, WvT,
        1024, 1024, 1024, vpT, 0, bv, 1.f, 0, 0, 0, nullptr, nullptr, nullptr);

    for (int c = 0; c < nchunks; c++){
      const size_t boff = (size_t)c * nb;
      gemm128<1, 1><<<dim3(16, 16, nb), B, 0, stream>>>(nullptr,
          qp + boff * 2048 * 1024, nullptr, kp + boff * 2048 * 1024,
          1024, 1024, 1024, S, 2048, nullptr, 0.03125f,
          2048ull * 1024, 2048ull * 1024, 2048ull * 2048, nullptr, nullptr, nullptr);
      softmax_rows<<<dim3(nb * 512, 1, 1), B, 0, stream>>>(S);
      gemm128<1, 1><<<dim3(8, 16, nb), B, 0, stream>>>(nullptr,
          S, nullptr, vpT + boff * 1024 * 2048,
          2048, 2048, 2048, x + boff * 2048 * 1024, 1024, nullptr, 1.f,
          2048ull * 2048, 1024ull * 2048, 2048ull * 1024, nullptr, nullptr, nullptr);
    }

    gemm128<2, 2><<<dim3(8, 128, 1), B, 0, stream>>>(nullptr, qp, x, WgT,
        1024, 2048, 2048, out, 1024, bg, 1.f, 0, 0, 0, x, mask, q);
  }
}

// Round 7
// 586.019 us; speedup vs baseline: 5.0607x; 1.1142x over previous
//
#include <hip/hip_runtime.h>

typedef unsigned int u32;
typedef unsigned short u16;
using v4f    = __attribute__((ext_vector_type(4))) float;
using short8 = __attribute__((ext_vector_type(8))) short;

#define GAS __attribute__((address_space(1)))
#define LAS __attribute__((address_space(3)))

// ---- bf16 helpers (RNE, matches HW convert; inputs are finite) ----
__device__ __forceinline__ u16 f2bf(float f){
  u32 u = __builtin_bit_cast(u32, f);
  u32 r = (u + 0x7fffu + ((u >> 16) & 1u)) >> 16;
  return (u16)r;
}
__device__ __forceinline__ float bf2f(u16 h){
  u32 u = ((u32)h) << 16;
  return __builtin_bit_cast(float, u);
}

// async global->LDS, 16B per lane. LDS dest must be wave-uniform base + lane*16.
__device__ __forceinline__ void gld_lds16(const void* g, void* l){
  __builtin_amdgcn_global_load_lds((const GAS u32*)g, (LAS u32*)l, 16, 0, 0);
}

// ---- fp32 -> bf16 bulk convert: 8 elems/thread, no tail (n % 2048 == 0) ----
__global__ __launch_bounds__(256) void cvt_f32_bf16(
    const float* __restrict__ in, u16* __restrict__ out)
{
  const size_t i = ((size_t)blockIdx.x * 256 + threadIdx.x) * 8;
  v4f lo = *(const v4f*)(in + i);
  v4f hi = *(const v4f*)(in + i + 4);
  u32 p0 = (u32)f2bf(lo.x) | ((u32)f2bf(lo.y) << 16);
  u32 p1 = (u32)f2bf(lo.z) | ((u32)f2bf(lo.w) << 16);
  u32 p2 = (u32)f2bf(hi.x) | ((u32)f2bf(hi.y) << 16);
  u32 p3 = (u32)f2bf(hi.z) | ((u32)f2bf(hi.w) << 16);
  *(uint4*)(out + i) = make_uint4(p0, p1, p2, p3);
}

// ---- transpose fp32 [K][N] -> bf16 [N][K] (weights only) ----
__global__ __launch_bounds__(256) void transpose_w_bf16(
    const float* __restrict__ in, u16* __restrict__ out, int K, int N)
{
  __shared__ float t[64][65];
  const int k0 = blockIdx.x * 64, n0 = blockIdx.y * 64;
  const int tx = threadIdx.x & 63, ty = threadIdx.x >> 6;
  #pragma unroll
  for (int i = 0; i < 16; i++){
    int r = ty + i * 4;
    t[r][tx] = in[(size_t)(k0 + r) * N + (n0 + tx)];
  }
  __syncthreads();
  #pragma unroll
  for (int i = 0; i < 16; i++){
    int r = ty + i * 4;
    out[(size_t)(n0 + r) * K + (k0 + tx)] = f2bf(t[tx][r]);
  }
}

// ---- in-place softmax, one WAVE per 2048-elem row (4 rows/block) ----
__global__ __launch_bounds__(256) void softmax_rows(u16* __restrict__ S){
  const int lane = threadIdx.x & 63, wid = threadIdx.x >> 6;
  u16* p = S + ((size_t)blockIdx.x * 4 + wid) * 2048;
  uint4 u[4];
  #pragma unroll
  for (int j = 0; j < 4; j++) u[j] = ((const uint4*)p)[lane + j * 64];
  float f[32];
  #pragma unroll
  for (int j = 0; j < 4; j++){
    u32 w4[4] = {u[j].x, u[j].y, u[j].z, u[j].w};
    #pragma unroll
    for (int i = 0; i < 4; i++){
      f[j * 8 + 2*i]     = bf2f((u16)(w4[i] & 0xffffu));
      f[j * 8 + 2*i + 1] = bf2f((u16)(w4[i] >> 16));
    }
  }
  float m = f[0];
  #pragma unroll
  for (int i = 1; i < 32; i++) m = fmaxf(m, f[i]);
  #pragma unroll
  for (int o = 32; o >= 1; o >>= 1) m = fmaxf(m, __shfl_xor(m, o));
  float s = 0.f;
  #pragma unroll
  for (int i = 0; i < 32; i++){ f[i] = __expf(f[i] - m); s += f[i]; }
  #pragma unroll
  for (int o = 32; o >= 1; o >>= 1) s += __shfl_xor(s, o);
  const float inv = 1.f / s;
  #pragma unroll
  for (int j = 0; j < 4; j++){
    u32 w4[4];
    #pragma unroll
    for (int i = 0; i < 4; i++)
      w4[i] = (u32)f2bf(f[j * 8 + 2*i] * inv) |
              ((u32)f2bf(f[j * 8 + 2*i + 1] * inv) << 16);
    ((uint4*)p)[lane + j * 64] = make_uint4(w4[0], w4[1], w4[2], w4[3]);
  }
}

// ===========================================================================
// 256x256x64 bf16 GEMM -- faithful m201 8-phase schedule (T2+T3+T4+T5).
//   512 thr = 8 waves (2M x 4N), per-wave C = 128x64 (acc[8][4]).
//   Iteration = 2 K-tiles (buf0 even, buf1 odd), 8 phases.
//   Phase = { ds-read quadrant frags ; stage 1 unit (2 gld) ; BARRIER ;
//             lgkmcnt(0) ; sched_barrier(0) ; setprio(1) ; 16 MFMA ;
//             setprio(0) ; BARRIER }
//   Quadrant order per K-tile: (rh0,c0),(rh0,c1),(rh1,c0),(rh1,c1) --
//   a-frags reused across c-phases, b-frags across rh-phases, so each phase
//   RETIRES one LDS unit; the NEXT phase's stage overwrites it (WAR-safe:
//   retire = reads done before lgkmcnt(0), which precedes the closing
//   barrier every other wave passes before staging).
//   Stage units/tile: S0=A rows{q,128+q}, S1=B cols even-32s, S2=B odd-32s,
//   S3=A rows{64+q,192+q}; staged P2,P3,P4,P5 (tile t+2 -> buf0) and
//   P6,P7,P8,P1' (tile t+3 -> buf1). vmcnt(6)=2 gld x 3 units in flight,
//   ONLY at P4/P8 (m218: counted-vs-drain0 is THE lever). Last iter P4
//   uses vmcnt(0) (trailing stages guarded off -> counted wait under-waits).
// LDS swizzle: slot (r,c8) holds global chunk c8^(r&7); reads same XOR.
// AMODE: 1 = A bf16, 2 = A concat(qp,x) bf16 (K split 1024, wave-uniform)
// EPI:   0 = +bias bf16  1 = *scale bf16  2 = gate-fused fp32
//        3 = +bias bf16 TRANSPOSED [batch][col][rowlocal]
// ===========================================================================
#define RD_A(BUFP, RH)                                                       \
  do{ _Pragma("unroll") for (int f = 0; f < 4; f++){                         \
    af[f][0] = *(const short8*)((BUFP) + ((RH)*4+f)*1024 + ch0);             \
    af[f][1] = *(const short8*)((BUFP) + ((RH)*4+f)*1024 + ch4); } }while(0)

#define RD_B(BUFP, BX, C)                                                    \
  do{ _Pragma("unroll") for (int cf = 0; cf < 2; cf++){                      \
    BX[cf][0] = *(const short8*)((BUFP) + ((C)*2+cf)*1024 + ch0);            \
    BX[cf][1] = *(const short8*)((BUFP) + ((C)*2+cf)*1024 + ch4); } }while(0)

#define MM16(RH, C, BX)                                                      \
  do{ _Pragma("unroll") for (int f = 0; f < 4; f++){                         \
    acc[(RH)*4+f][(C)*2]   = __builtin_amdgcn_mfma_f32_16x16x32_bf16(        \
        af[f][0], BX[0][0], acc[(RH)*4+f][(C)*2],   0, 0, 0);                \
    acc[(RH)*4+f][(C)*2]   = __builtin_amdgcn_mfma_f32_16x16x32_bf16(        \
        af[f][1], BX[0][1], acc[(RH)*4+f][(C)*2],   0, 0, 0);                \
    acc[(RH)*4+f][(C)*2+1] = __builtin_amdgcn_mfma_f32_16x16x32_bf16(        \
        af[f][0], BX[1][0], acc[(RH)*4+f][(C)*2+1], 0, 0, 0);                \
    acc[(RH)*4+f][(C)*2+1] = __builtin_amdgcn_mfma_f32_16x16x32_bf16(        \
        af[f][1], BX[1][1], acc[(RH)*4+f][(C)*2+1], 0, 0, 0); } }while(0)

#define PH_OPEN()                                                            \
  __builtin_amdgcn_s_barrier();                                              \
  asm volatile("s_waitcnt lgkmcnt(0)" ::: "memory");                         \
  __builtin_amdgcn_sched_barrier(0);                                         \
  __builtin_amdgcn_s_setprio(1)

#define PH_CLOSE()                                                           \
  __builtin_amdgcn_s_setprio(0);                                             \
  asm volatile("" ::: "memory");                                             \
  __builtin_amdgcn_s_barrier();                                              \
  asm volatile("" ::: "memory")

template<int AMODE, int EPI>
__global__ __launch_bounds__(512) void gemm8p(
    const u16* __restrict__ Ab,
    const u16* __restrict__ A2b,
    const u16* __restrict__ BT,
    int lda, int ldb, int K,
    void* __restrict__ Cout, int ldc,
    const float* __restrict__ bias, float scale,
    size_t aBatch, size_t bBatch, size_t cBatch,
    const u16* __restrict__ xg,
    const float* __restrict__ maskp,
    const float* __restrict__ q0p)
{
  constexpr int BK = 64;
  __shared__ __align__(16) u16 As[2][256 * 64];   // 32 KB per buf
  __shared__ __align__(16) u16 Bs[2][256 * 64];

  const int z    = blockIdx.z;
  const int gx   = (int)gridDim.x;
  const int lin  = (int)blockIdx.y * gx + (int)blockIdx.x;
  const int l2gx = 31 - __clz(gx);
  const int g    = lin >> (3 + l2gx);
  const int rem  = lin & ((gx << 3) - 1);
  const int m0   = ((g << 3) + (rem & 7)) * 256;
  const int n0   = (rem >> 3) * 256;

  const int tid  = (int)threadIdx.x;
  const int lane = tid & 63, wid = tid >> 6;
  const int wm   = (wid >> 2) * 128;
  const int wn   = (wid & 3) * 64;

  const u16* Az = Ab + (size_t)z * aBatch;
  const u16* Bz = BT + (size_t)z * bBatch;

  // ---- stage-unit addressing (per-thread constants) ----
  // A unit u: rows {q+u*64, q+u*64+128}; B unit u: col-rows even/odd 32-groups
  const int qrow = tid >> 3, c8 = tid & 7;
  u32 aG[2][2], aL[2][2], bG[2][2], bL[2][2];
  #pragma unroll
  for (int u = 0; u < 2; u++)
    #pragma unroll
    for (int j = 0; j < 2; j++){
      int ra = qrow + u * 64 + j * 128;
      int ca = c8 ^ (ra & 7);
      aG[u][j] = (u32)(((m0 + ra) * lda + ca * 8) * 2);
      aL[u][j] = (u32)(ra * 128 + c8 * 16);
      int rb = (qrow & 31) + (qrow >> 5) * 64 + u * 32 + j * 128;
      int cb = c8 ^ (rb & 7);
      bG[u][j] = (u32)(((n0 + rb) * ldb + cb * 8) * 2);
      bL[u][j] = (u32)(rb * 128 + c8 * 16);
    }

  auto stA = [&](int kt, int bf, int u){
    const u16* src; u32 ka;
    if (AMODE == 2){
      src = (kt * BK < 1024) ? Az : A2b;
      ka = (u32)(((kt * BK) & 1023) * 2);
    } else {
      src = Az;
      ka = (u32)(kt * BK * 2);
    }
    #pragma unroll
    for (int j = 0; j < 2; j++)
      gld_lds16((const char*)src + aG[u][j] + ka, (char*)&As[bf][0] + aL[u][j]);
  };
  auto stB = [&](int kt, int bf, int u){
    const u32 kb = (u32)(kt * BK * 2);
    #pragma unroll
    for (int j = 0; j < 2; j++)
      gld_lds16((const char*)Bz + bG[u][j] + kb, (char*)&Bs[bf][0] + bL[u][j]);
  };

  v4f acc[8][4];
  #pragma unroll
  for (int mi = 0; mi < 8; mi++)
    #pragma unroll
    for (int ni = 0; ni < 4; ni++)
      acc[mi][ni] = (v4f){0.f, 0.f, 0.f, 0.f};

  // read-side swizzle: per-lane constant chunk offsets (elements)
  const int ll  = lane & 15, lq = lane >> 4;
  const int ch0 = ((0 + lq) ^ (ll & 7)) << 3;   // k 0..31
  const int ch4 = ((4 + lq) ^ (ll & 7)) << 3;   // k 32..63

  const u16* aP0 = &As[0][0] + (wm + ll) * 64;
  const u16* bP0 = &Bs[0][0] + (wn + ll) * 64;
  const u16* aP1 = &As[1][0] + (wm + ll) * 64;
  const u16* bP1 = &Bs[1][0] + (wn + ll) * 64;

  // ---- prologue: tile0 full -> buf0; tile1 units S0,S1,S2 -> buf1 (14 gld)
  stA(0, 0, 0); stA(0, 0, 1); stB(0, 0, 0); stB(0, 0, 1);
  stA(1, 1, 0); stB(1, 1, 0); stB(1, 1, 1);
  asm volatile("s_waitcnt vmcnt(6)" ::: "memory");   // tile0's 8 landed
  __builtin_amdgcn_s_barrier();
  asm volatile("" ::: "memory");

  const int nt = K / BK;          // even, >= 4 for all launches here
  const int nIter = nt >> 1;
  short8 af[4][2], bf0[2][2], bf1[2][2];

  for (int it = 0; it < nIter; it++){
    const int t0 = 2 * it, t1 = t0 + 1;
    const bool s2 = (t0 + 2 < nt);     // stage tile t0+2 -> buf0
    const bool s3 = (t0 + 3 < nt);     // stage tile t0+3 -> buf1
    const bool lastIt = (it == nIter - 1);

    // -------- K-tile t0 (buf0) --------
    // P1: quadrant (rh0,c0); stage S3(t1) -> buf1
    RD_A(aP0, 0); RD_B(bP0, bf0, 0);
    stA(t1, 1, 1);
    PH_OPEN(); MM16(0, 0, bf0); PH_CLOSE();
    // P2: (rh0,c1); stage S0(t0+2) -> buf0 (A rows {q,128+q} retired in P1)
    RD_B(bP0, bf1, 1);
    if (s2) stA(t0 + 2, 0, 0);
    PH_OPEN(); MM16(0, 1, bf1); PH_CLOSE();
    // P3: (rh1,c0); stage S1(t0+2) (B even cols retired in P1)
    RD_A(aP0, 1);
    if (s2) stB(t0 + 2, 0, 0);
    PH_OPEN(); MM16(1, 0, bf0); PH_CLOSE();
    // P4: (rh1,c1); stage S2(t0+2) (B odd cols retired in P2); counted vmcnt
    if (s2) stB(t0 + 2, 0, 1);
    PH_OPEN(); MM16(1, 1, bf1);
    __builtin_amdgcn_s_setprio(0);
    if (lastIt) asm volatile("s_waitcnt vmcnt(0)" ::: "memory");
    else        asm volatile("s_waitcnt vmcnt(6)" ::: "memory");
    asm volatile("" ::: "memory");
    __builtin_amdgcn_s_barrier();
    asm volatile("" ::: "memory");

    // -------- K-tile t1 (buf1) --------
    // P5: (rh0,c0); stage S3(t0+2) -> buf0 (A rh1 of buf0 retired in P3)
    RD_A(aP1, 0); RD_B(bP1, bf0, 0);
    if (s2) stA(t0 + 2, 0, 1);
    PH_OPEN(); MM16(0, 0, bf0); PH_CLOSE();
    // P6: (rh0,c1); stage S0(t0+3) -> buf1 (A rh0 of buf1 retired in P5)
    RD_B(bP1, bf1, 1);
    if (s3) stA(t0 + 3, 1, 0);
    PH_OPEN(); MM16(0, 1, bf1); PH_CLOSE();
    // P7: (rh1,c0); stage S1(t0+3)
    RD_A(aP1, 1);
    if (s3) stB(t0 + 3, 1, 0);
    PH_OPEN(); MM16(1, 0, bf0); PH_CLOSE();
    // P8: (rh1,c1); stage S2(t0+3); counted vmcnt guards next-P1 (buf0 ready)
    if (s3) stB(t0 + 3, 1, 1);
    PH_OPEN(); MM16(1, 1, bf1);
    __builtin_amdgcn_s_setprio(0);
    asm volatile("s_waitcnt vmcnt(6)" ::: "memory");
    asm volatile("" ::: "memory");
    __builtin_amdgcn_s_barrier();
    asm volatile("" ::: "memory");
  }

  // epilogue: C/D layout col = lane&15, row = (lane>>4)*4 + r (m89/m91)
  const int lr = lq * 4, lc = ll;
  if (EPI == 0 || EPI == 1){
    u16* C = (u16*)Cout + (size_t)z * cBatch;
    #pragma unroll
    for (int mi = 0; mi < 8; mi++){
      #pragma unroll
      for (int ni = 0; ni < 4; ni++){
        int col = n0 + wn + ni * 16 + lc;
        float bv = (EPI == 0) ? bias[col] : 0.f;
        #pragma unroll
        for (int r = 0; r < 4; r++){
          int row = m0 + wm + mi * 16 + lr + r;
          C[(size_t)row * ldc + col] = f2bf(acc[mi][ni][r] * scale + bv);
        }
      }
    }
  } else if (EPI == 3){
    u16* C = (u16*)Cout;
    #pragma unroll
    for (int mi = 0; mi < 8; mi++){
      int rowb = m0 + wm + mi * 16 + lr;        // multiple of 4, single batch
      int bb   = rowb >> 11;
      int rloc = rowb & 2047;
      #pragma unroll
      for (int ni = 0; ni < 4; ni++){
        int col = n0 + wn + ni * 16 + lc;
        float bv = bias[col];
        u32 pk0 = (u32)f2bf(acc[mi][ni][0] + bv) | ((u32)f2bf(acc[mi][ni][1] + bv) << 16);
        u32 pk1 = (u32)f2bf(acc[mi][ni][2] + bv) | ((u32)f2bf(acc[mi][ni][3] + bv) << 16);
        *(uint2*)&C[(size_t)bb * (1024ull * 2048) + (size_t)col * 2048 + rloc] =
            make_uint2(pk0, pk1);
      }
    }
  } else {
    float* C = (float*)Cout;
    #pragma unroll
    for (int mi = 0; mi < 8; mi++){
      #pragma unroll
      for (int ni = 0; ni < 4; ni++){
        int col = n0 + wn + ni * 16 + lc;
        float bv = bias[col];
        #pragma unroll
        for (int r = 0; r < 4; r++){
          int row = m0 + wm + mi * 16 + lr + r;
          float gg = acc[mi][ni][r] + bv;
          float sg = 1.f / (1.f + __expf(-gg));
          float xv = bf2f(xg[(size_t)row * 1024 + col]);
          C[(size_t)row * ldc + col] =
              xv * maskp[row] * sg + q0p[(size_t)row * 1024 + col];
        }
      }
    }
  }
}
#undef RD_A
#undef RD_B
#undef MM16
#undef PH_OPEN
#undef PH_CLOSE

// ---- 128x128x64 kernel kept for the small-workspace fallback path ----
template<int AMODE, int EPI>
__global__ __launch_bounds__(256) void gemm128(
    const float* __restrict__ Af,
    const u16* __restrict__ Ab,
    const u16* __restrict__ A2b,
    const u16* __restrict__ BT,
    int lda, int ldb, int K,
    void* __restrict__ Cout, int ldc,
    const float* __restrict__ bias, float scale,
    size_t aBatch, size_t bBatch, size_t cBatch,
    const u16* __restrict__ xg,
    const float* __restrict__ maskp,
    const float* __restrict__ q0p)
{
  constexpr int BM = 128, BN = 128, BK = 64;
  __shared__ __align__(16) u16 As[BM * BK];
  __shared__ __align__(16) u16 Bs[BN * BK];
  const int z   = blockIdx.z;
  const int lin  = blockIdx.y * gridDim.x + blockIdx.x;
  const int l2gx = 31 - __clz((int)gridDim.x);
  const int g    = lin >> (3 + l2gx);
  const int rem  = lin & (((int)gridDim.x << 3) - 1);
  const int m0   = ((g << 3) + (rem & 7)) * BM;
  const int n0   = (rem >> 3) * BN;
  const int tid = threadIdx.x;
  const int lane = tid & 63, wid = tid >> 6;
  const int wm = (wid >> 1) * 64, wn = (wid & 1) * 64;
  const u16* Abz = Ab + (size_t)z * aBatch;
  const u16* BTz = BT + (size_t)z * bBatch;

  v4f acc[4][4];
  #pragma unroll
  for (int mi = 0; mi < 4; mi++)
    #pragma unroll
    for (int ni = 0; ni < 4; ni++)
      acc[mi][ni] = (v4f){0.f, 0.f, 0.f, 0.f};

  for (int k0 = 0; k0 < K; k0 += BK){
    if (AMODE == 0){
      #pragma unroll
      for (int i = 0; i < 4; i++){
        int idx = tid + i * 256;
        int r = idx >> 3, s = idx & 7;
        const float* src = Af + (size_t)(m0 + r) * lda + (k0 + s * 8);
        v4f lo = ((const v4f*)src)[0];
        v4f hi = ((const v4f*)src)[1];
        u32 p0 = (u32)f2bf(lo.x) | ((u32)f2bf(lo.y) << 16);
        u32 p1 = (u32)f2bf(lo.z) | ((u32)f2bf(lo.w) << 16);
        u32 p2 = (u32)f2bf(hi.x) | ((u32)f2bf(hi.y) << 16);
        u32 p3 = (u32)f2bf(hi.z) | ((u32)f2bf(hi.w) << 16);
        *(uint4*)&As[(size_t)idx * 8] = make_uint4(p0, p1, p2, p3);
      }
    } else {
      #pragma unroll
      for (int i = 0; i < 4; i++){
        int idx = tid + i * 256;
        int r = idx >> 3, s = idx & 7;
        int kk = k0 + s * 8;
        const u16* src;
        if (AMODE == 2){
          src = (kk < 1024) ? (Abz + (size_t)(m0 + r) * 1024 + kk)
                            : (A2b + (size_t)(m0 + r) * 1024 + (kk - 1024));
        } else {
          src = Abz + (size_t)(m0 + r) * lda + kk;
        }
        gld_lds16(src, &As[(size_t)idx * 8]);
      }
    }
    #pragma unroll
    for (int i = 0; i < 4; i++){
      int idx = tid + i * 256;
      int r = idx >> 3, s = idx & 7;
      gld_lds16(BTz + (size_t)(n0 + r) * ldb + (k0 + s * 8), &Bs[(size_t)idx * 8]);
    }
    __syncthreads();
    #pragma unroll
    for (int ks = 0; ks < BK; ks += 32){
      short8 a[4], b[4];
      #pragma unroll
      for (int mi = 0; mi < 4; mi++)
        a[mi] = *(const short8*)&As[(wm + mi * 16 + (lane & 15)) * BK + ks + (lane >> 4) * 8];
      #pragma unroll
      for (int ni = 0; ni < 4; ni++)
        b[ni] = *(const short8*)&Bs[(wn + ni * 16 + (lane & 15)) * BK + ks + (lane >> 4) * 8];
      #pragma unroll
      for (int mi = 0; mi < 4; mi++)
        #pragma unroll
        for (int ni = 0; ni < 4; ni++)
          acc[mi][ni] = __builtin_amdgcn_mfma_f32_16x16x32_bf16(a[mi], b[ni], acc[mi][ni], 0, 0, 0);
    }
    __syncthreads();
  }

  const int lr = (lane >> 4) * 4, lc = lane & 15;
  if (EPI == 0 || EPI == 1){
    u16* C = (u16*)Cout + (size_t)z * cBatch;
    #pragma unroll
    for (int mi = 0; mi < 4; mi++){
      #pragma unroll
      for (int ni = 0; ni < 4; ni++){
        int col = n0 + wn + ni * 16 + lc;
        float bv = (EPI == 0) ? bias[col] : 0.f;
        #pragma unroll
        for (int r = 0; r < 4; r++){
          int row = m0 + wm + mi * 16 + lr + r;
          C[(size_t)row * ldc + col] = f2bf(acc[mi][ni][r] * scale + bv);
        }
      }
    }
  } else if (EPI == 3){
    u16* C = (u16*)Cout;
    #pragma unroll
    for (int mi = 0; mi < 4; mi++){
      int rowb = m0 + wm + mi * 16 + lr;
      int b    = rowb >> 11;
      int rloc = rowb & 2047;
      #pragma unroll
      for (int ni = 0; ni < 4; ni++){
        int col = n0 + wn + ni * 16 + lc;
        float bv = bias[col];
        u32 pk[2];
        pk[0] = (u32)f2bf(acc[mi][ni][0] + bv) | ((u32)f2bf(acc[mi][ni][1] + bv) << 16);
        pk[1] = (u32)f2bf(acc[mi][ni][2] + bv) | ((u32)f2bf(acc[mi][ni][3] + bv) << 16);
        *(uint2*)&C[(size_t)b * (1024ull * 2048) + (size_t)col * 2048 + rloc] =
            make_uint2(pk[0], pk[1]);
      }
    }
  } else {
    float* C = (float*)Cout;
    #pragma unroll
    for (int mi = 0; mi < 4; mi++){
      #pragma unroll
      for (int ni = 0; ni < 4; ni++){
        int col = n0 + wn + ni * 16 + lc;
        float bv = bias[col];
        #pragma unroll
        for (int r = 0; r < 4; r++){
          int row = m0 + wm + mi * 16 + lr + r;
          float g  = acc[mi][ni][r] + bv;
          float sg = 1.f / (1.f + __expf(-g));
          float xv = bf2f(xg[(size_t)row * 1024 + col]);
          C[(size_t)row * ldc + col] =
              xv * maskp[row] * sg + q0p[(size_t)row * 1024 + col];
        }
      }
    }
  }
}

// ---------------------------------------------------------------------------
// B=8, L=2048, D=1024. All inputs fp32. Pipeline (bigws):
//   1. Wq/Wk/Wv/Wg -> bf16 transposed ([N][K]) in ws
//   2. per tensor: fp32->bf16 into tmp, then 8-phase proj GEMM;
//      V proj stores TRANSPOSED -> vpT [b][d][l]
//   3. per chunk: S = qp kp^T /32 ; softmax ; x = P V
//   4. gate GEMM over concat(qp,x) with fused sigmoid/mask/residual epilogue
// All big GEMMs: 256x256x64 8-phase (m201 schedule), 128KB LDS.
// ---------------------------------------------------------------------------
extern "C" void kernel_launch(void* const* d_in, const int* in_sizes, int n_in,
                              void* d_out, int out_size, void* d_ws, size_t ws_size,
                              hipStream_t stream)
{
  const float* q    = (const float*)d_in[0];
  const float* k    = (const float*)d_in[1];
  const float* v    = (const float*)d_in[2];
  const float* mask = (const float*)d_in[3];
  const float* Wq   = (const float*)d_in[4];
  const float* bq   = (const float*)d_in[5];
  const float* Wk   = (const float*)d_in[6];
  const float* bk   = (const float*)d_in[7];
  const float* Wv   = (const float*)d_in[8];
  const float* bv   = (const float*)d_in[9];
  const float* Wg   = (const float*)d_in[10];
  const float* bg   = (const float*)d_in[11];
  float* out = (float*)d_out;

  char* ws = (char*)d_ws;
  const size_t MB = 1024ull * 1024ull;
  u16* WqT = (u16*)(ws + 0 * MB);    // [1024][1024] bf16
  u16* WkT = (u16*)(ws + 2 * MB);
  u16* WvT = (u16*)(ws + 4 * MB);
  u16* WgT = (u16*)(ws + 6 * MB);    // [1024][2048] bf16
  u16* qp  = (u16*)(ws + 10 * MB);   // [16384][1024] bf16
  u16* kp  = (u16*)(ws + 42 * MB);   // [16384][1024] bf16 ; x overlays per batch
  u16* vpT = (u16*)(ws + 74 * MB);   // [8][1024][2048] bf16 (V proj, transposed)
  u16* S   = (u16*)(ws + 106 * MB);  // [nb][2048][2048] bf16, reused per chunk
  u16* tmp = (u16*)(ws + 106 * MB);  // [16384][1024] bf16 convert scratch (dies before S)
  u16* x   = kp;

  const bool bigws = ws_size >= 138 * MB;
  int nb = 8;
  while (nb > 1 && 106 * MB + (size_t)nb * 8 * MB > ws_size) nb >>= 1;
  const int nchunks = 8 / nb;

  dim3 B(256);
  dim3 T5(512);

  // 1. weights -> bf16, transposed to [N][K]
  transpose_w_bf16<<<dim3(16, 16, 1), B, 0, stream>>>(Wq, WqT, 1024, 1024);
  transpose_w_bf16<<<dim3(16, 16, 1), B, 0, stream>>>(Wk, WkT, 1024, 1024);
  transpose_w_bf16<<<dim3(16, 16, 1), B, 0, stream>>>(Wv, WvT, 1024, 1024);
  transpose_w_bf16<<<dim3(32, 16, 1), B, 0, stream>>>(Wg, WgT, 2048, 1024);

  if (bigws){
    // 2. projections: cvt fp32->bf16, then [16384,1024] x [1024,1024]
    cvt_f32_bf16<<<dim3(8192), B, 0, stream>>>(q, tmp);
    gemm8p<1, 0><<<dim3(4, 64, 1), T5, 0, stream>>>(tmp, nullptr, WqT,
        1024, 1024, 1024, qp, 1024, bq, 1.f, 0, 0, 0, nullptr, nullptr, nullptr);
    cvt_f32_bf16<<<dim3(8192), B, 0, stream>>>(k, tmp);
    gemm8p<1, 0><<<dim3(4, 64, 1), T5, 0, stream>>>(tmp, nullptr, WkT,
        1024, 1024, 1024, kp, 1024, bk, 1.f, 0, 0, 0, nullptr, nullptr, nullptr);
    cvt_f32_bf16<<<dim3(8192), B, 0, stream>>>(v, tmp);
    gemm8p<1, 3><<<dim3(4, 64, 1), T5, 0, stream>>>(tmp, nullptr, WvT,
        1024, 1024, 1024, vpT, 0, bv, 1.f, 0, 0, 0, nullptr, nullptr, nullptr);

    // 3. attention middle, nb batches at a time
    for (int c = 0; c < nchunks; c++){
      const size_t boff = (size_t)c * nb;
      gemm8p<1, 1><<<dim3(8, 8, nb), T5, 0, stream>>>(
          qp + boff * 2048 * 1024, nullptr, kp + boff * 2048 * 1024,
          1024, 1024, 1024, S, 2048, nullptr, 0.03125f,
          2048ull * 1024, 2048ull * 1024, 2048ull * 2048, nullptr, nullptr, nullptr);
      softmax_rows<<<dim3(nb * 512, 1, 1), B, 0, stream>>>(S);
      gemm8p<1, 1><<<dim3(4, 8, nb), T5, 0, stream>>>(
          S, nullptr, vpT + boff * 1024 * 2048,
          2048, 2048, 2048, x + boff * 2048 * 1024, 1024, nullptr, 1.f,
          2048ull * 2048, 1024ull * 2048, 2048ull * 1024, nullptr, nullptr, nullptr);
    }

    // 4. gate GEMM over concat(qp, x) + fused epilogue -> fp32 out
    gemm8p<2, 2><<<dim3(4, 64, 1), T5, 0, stream>>>(qp, x, WgT,
        1024, 2048, 2048, out, 1024, bg, 1.f, 0, 0, 0, x, mask, q);
  } else {
    // fallback: original 128^2 pipeline with fp32 staging projections
    gemm128<0, 0><<<dim3(8, 128, 1), B, 0, stream>>>(q, nullptr, nullptr, WqT,
        1024, 1024, 1024, qp, 1024, bq, 1.f, 0, 0, 0, nullptr, nullptr, nullptr);
    gemm128<0, 0><<<dim3(8, 128, 1), B, 0, stream>>>(k, nullptr, nullptr, WkT,
        1024, 1024, 1024, kp, 1024, bk, 1.f, 0, 0, 0, nullptr, nullptr, nullptr);
    gemm128<0, 3><<<dim3(8, 128, 1), B, 0, stream>>>(v, nullptr, nullptr, WvT,
        1024, 1024, 1024, vpT, 0, bv, 1.f, 0, 0, 0, nullptr, nullptr, nullptr);

    for (int c = 0; c < nchunks; c++){
      const size_t boff = (size_t)c * nb;
      gemm128<1, 1><<<dim3(16, 16, nb), B, 0, stream>>>(nullptr,
          qp + boff * 2048 * 1024, nullptr, kp + boff * 2048 * 1024,
          1024, 1024, 1024, S, 2048, nullptr, 0.03125f,
          2048ull * 1024, 2048ull * 1024, 2048ull * 2048, nullptr, nullptr, nullptr);
      softmax_rows<<<dim3(nb * 512, 1, 1), B, 0, stream>>>(S);
      gemm128<1, 1><<<dim3(8, 16, nb), B, 0, stream>>>(nullptr,
          S, nullptr, vpT + boff * 1024 * 2048,
          2048, 2048, 2048, x + boff * 2048 * 1024, 1024, nullptr, 1.f,
          2048ull * 2048, 1024ull * 2048, 2048ull * 1024, nullptr, nullptr, nullptr);
    }

    gemm128<2, 2><<<dim3(8, 128, 1), B, 0, stream>>>(nullptr, qp, x, WgT,
        1024, 2048, 2048, out, 1024, bg, 1.f, 0, 0, 0, x, mask, q);
  }
}